// Round 4
// baseline (34.790 us; speedup 1.0000x reference)
//
#include <hip/hip_runtime.h>
#include <hip/hip_fp16.h>

#define NUM_F  39
#define NUM_P  741      // 39*38/2
#define NT     48       // tiles, padded (47 real + 1 pad)
#define NPAD   768      // NT * 16
#define DIM    64
#define ESTRH  72       // padded fp16 row stride (halves)

typedef float    f32x4 __attribute__((ext_vector_type(4)));
typedef _Float16 f16x8 __attribute__((ext_vector_type(8)));

union H8 {
    f16x8    v;
    __half2  h2[4];
    _Float16 h[8];
};

__global__ __launch_bounds__(256, 3) void afm_mfma3(
    const int*   __restrict__ feat_index,   // [B, F]
    const float* __restrict__ feat_value,   // [B, F]
    const float* __restrict__ fo_w,         // [NUM_FEATS, 1]
    const float* __restrict__ emb_table,    // [NUM_FEATS, 64]
    const float* __restrict__ att_W,        // [64, 64] (d, a)
    const float* __restrict__ att_b,        // [64]
    const float* __restrict__ att_h,        // [64]
    const float* __restrict__ p_vec,        // [64]
    const float* __restrict__ bias,         // [1]
    float*       __restrict__ out)          // [B]
{
    const int b    = blockIdx.x;
    const int t    = threadIdx.x;
    const int wave = t >> 6;
    const int lane = t & 63;
    const int la   = lane & 15;   // pair-within-tile (B col / C col)
    const int lg   = lane >> 4;   // k-group / C row-group

    __shared__ __half         e_lds[NUM_F][ESTRH];  // scaled embeddings, fp16
    __shared__ __half         Wt[DIM][ESTRH];       // W^T fp16: Wt[a][d]
    __shared__ float2         sq_s[NPAD];           // {sig, q}
    __shared__ float          b_lds[DIM], h_lds[DIM], pv_lds[DIM];
    __shared__ unsigned short pairRC[NPAD];         // (r<<8)|c
    __shared__ int            s_idx[NUM_F];
    __shared__ float          s_fv[NUM_F];
    __shared__ float          s_yfirst;
    __shared__ float          wred[12];             // wave partials: max, S, Q

    // ---------------- phase 0: staging ----------------
    int   my_idx = 0;
    float my_fv  = 0.f;
    if (t < NUM_F) {
        my_idx   = feat_index[b * NUM_F + t];
        my_fv    = feat_value[b * NUM_F + t];
        s_idx[t] = my_idx;
        s_fv[t]  = my_fv;
    }
    if (t < DIM) {
        b_lds[t]  = att_b[t];
        h_lds[t]  = att_h[t];
        pv_lds[t] = p_vec[t];
    }
    if (t < NUM_F) {   // triu(k=1) pair map, row-major
        int r = t, off = r * (2 * NUM_F - r - 1) / 2;
        for (int c = r + 1; c < NUM_F; ++c) {
            pairRC[off] = (unsigned short)((r << 8) | c);
            ++off;
        }
    }
    if (t < NPAD - NUM_P) pairRC[NUM_P + t] = 0;   // pad tiles -> pair (0,0), stores guarded

    // W^T -> fp16 LDS
    for (int q = t; q < DIM * DIM; q += 256) {
        int d = q >> 6, a = q & 63;
        Wt[a][d] = (__half)(_Float16)att_W[q];
    }

    // y_first: wave 0 butterfly
    float yf = (t < NUM_F) ? fo_w[my_idx] * my_fv : 0.f;
    if (wave == 0) {
        #pragma unroll
        for (int m = 1; m < 64; m <<= 1) yf += __shfl_xor(yf, m);
        if (t == 0) s_yfirst = yf;
    }
    __syncthreads();

    // ---------------- phase 1: E staging (fp16) ----------------
    {
        const float4* emb4 = (const float4*)emb_table;
        for (int q = t; q < NUM_F * 8; q += 256) {
            int f = q >> 3, d8 = q & 7;
            float4 v0 = emb4[(size_t)s_idx[f] * 16 + d8 * 2];
            float4 v1 = emb4[(size_t)s_idx[f] * 16 + d8 * 2 + 1];
            float fv = s_fv[f];
            H8 hh;
            hh.h2[0] = __float22half2_rn(make_float2(v0.x * fv, v0.y * fv));
            hh.h2[1] = __float22half2_rn(make_float2(v0.z * fv, v0.w * fv));
            hh.h2[2] = __float22half2_rn(make_float2(v1.x * fv, v1.y * fv));
            hh.h2[3] = __float22half2_rn(make_float2(v1.z * fv, v1.w * fv));
            *(f16x8*)&e_lds[f][d8 * 8] = hh.v;
        }
    }
    __syncthreads();

    // ---------------- hoisted stationary fragments ----------------
    // A-frags = W^T tiles: lane holds row a = n*16+la, k(d) = kf*32 + lg*8 + j
    f16x8 WA[4][2];
    #pragma unroll
    for (int n = 0; n < 4; ++n)
        #pragma unroll
        for (int kf = 0; kf < 2; ++kf)
            WA[n][kf] = *(const f16x8*)&Wt[n * 16 + la][kf * 32 + lg * 8];

    // p_vec as row 0 of a 5th A-tile
    f16x8 PA[2];
    #pragma unroll
    for (int kf = 0; kf < 2; ++kf) {
        H8 P;
        #pragma unroll
        for (int j = 0; j < 8; ++j) {
            float x = (la == 0) ? pv_lds[kf * 32 + lg * 8 + j] : 0.f;
            P.h[j] = (_Float16)x;
        }
        PA[kf] = P.v;
    }

    // bias (accum init) and h, per lane's C rows: a = n*16 + lg*4 + i
    f32x4 b4[4], h4[4];
    #pragma unroll
    for (int n = 0; n < 4; ++n) {
        b4[n] = *(const f32x4*)&b_lds[n * 16 + lg * 4];
        h4[n] = *(const f32x4*)&h_lds[n * 16 + lg * 4];
    }

    // ---------------- phase 2: two independent tile-chains per iteration ----------------
    #pragma unroll 1
    for (int it = 0; it < 6; ++it) {
        const int tile0 = wave + it * 8;       // chains: tile0, tile0+4 (both < 48)

        int p_[2], r_[2], c_[2];
        #pragma unroll
        for (int u = 0; u < 2; ++u) {
            p_[u] = ((tile0 + u * 4) << 4) + la;
            const unsigned int rc = pairRC[p_[u]];
            r_[u] = (int)(rc >> 8);
            c_[u] = (int)(rc & 255u);
        }

        // B-frags = inter: col = la (pair), k(d) = kf*32 + lg*8 + j
        H8 B0_[2], B1_[2];
        #pragma unroll
        for (int u = 0; u < 2; ++u) {
            H8 er0, er1, ec0, ec1;
            er0.v = *(const f16x8*)&e_lds[r_[u]][lg * 8];
            er1.v = *(const f16x8*)&e_lds[r_[u]][32 + lg * 8];
            ec0.v = *(const f16x8*)&e_lds[c_[u]][lg * 8];
            ec1.v = *(const f16x8*)&e_lds[c_[u]][32 + lg * 8];
            #pragma unroll
            for (int i = 0; i < 4; ++i) {
                B0_[u].h2[i] = __hmul2(er0.h2[i], ec0.h2[i]);
                B1_[u].h2[i] = __hmul2(er1.h2[i], ec1.h2[i]);
            }
        }

        // Z^T tiles: D[a][pair], bias folded into init; 2 independent MFMA chains
        f32x4 a0_[2], a1_[2], a2_[2], a3_[2], aq_[2];
        #pragma unroll
        for (int u = 0; u < 2; ++u) {
            a0_[u] = b4[0]; a1_[u] = b4[1]; a2_[u] = b4[2]; a3_[u] = b4[3];
            aq_[u] = (f32x4){0.f, 0.f, 0.f, 0.f};
        }
        #pragma unroll
        for (int u = 0; u < 2; ++u) {
            a0_[u] = __builtin_amdgcn_mfma_f32_16x16x32_f16(WA[0][0], B0_[u].v, a0_[u], 0, 0, 0);
            a1_[u] = __builtin_amdgcn_mfma_f32_16x16x32_f16(WA[1][0], B0_[u].v, a1_[u], 0, 0, 0);
            a2_[u] = __builtin_amdgcn_mfma_f32_16x16x32_f16(WA[2][0], B0_[u].v, a2_[u], 0, 0, 0);
            a3_[u] = __builtin_amdgcn_mfma_f32_16x16x32_f16(WA[3][0], B0_[u].v, a3_[u], 0, 0, 0);
            aq_[u] = __builtin_amdgcn_mfma_f32_16x16x32_f16(PA[0],    B0_[u].v, aq_[u], 0, 0, 0);
            a0_[u] = __builtin_amdgcn_mfma_f32_16x16x32_f16(WA[0][1], B1_[u].v, a0_[u], 0, 0, 0);
            a1_[u] = __builtin_amdgcn_mfma_f32_16x16x32_f16(WA[1][1], B1_[u].v, a1_[u], 0, 0, 0);
            a2_[u] = __builtin_amdgcn_mfma_f32_16x16x32_f16(WA[2][1], B1_[u].v, a2_[u], 0, 0, 0);
            a3_[u] = __builtin_amdgcn_mfma_f32_16x16x32_f16(WA[3][1], B1_[u].v, a3_[u], 0, 0, 0);
            aq_[u] = __builtin_amdgcn_mfma_f32_16x16x32_f16(PA[1],    B1_[u].v, aq_[u], 0, 0, 0);
        }

        // epilogue: sig[pair] = sum_a relu(Zt[a][pair]) * h[a]; 4-way partial tree
        #pragma unroll
        for (int u = 0; u < 2; ++u) {
            float s0 = fmaxf(a0_[u][0], 0.f) * h4[0][0];
            float s1 = fmaxf(a1_[u][0], 0.f) * h4[1][0];
            float s2 = fmaxf(a2_[u][0], 0.f) * h4[2][0];
            float s3 = fmaxf(a3_[u][0], 0.f) * h4[3][0];
            s0 = fmaf(fmaxf(a0_[u][1], 0.f), h4[0][1], s0);
            s1 = fmaf(fmaxf(a1_[u][1], 0.f), h4[1][1], s1);
            s2 = fmaf(fmaxf(a2_[u][1], 0.f), h4[2][1], s2);
            s3 = fmaf(fmaxf(a3_[u][1], 0.f), h4[3][1], s3);
            s0 = fmaf(fmaxf(a0_[u][2], 0.f), h4[0][2], s0);
            s1 = fmaf(fmaxf(a1_[u][2], 0.f), h4[1][2], s1);
            s2 = fmaf(fmaxf(a2_[u][2], 0.f), h4[2][2], s2);
            s3 = fmaf(fmaxf(a3_[u][2], 0.f), h4[3][2], s3);
            s0 = fmaf(fmaxf(a0_[u][3], 0.f), h4[0][3], s0);
            s1 = fmaf(fmaxf(a1_[u][3], 0.f), h4[1][3], s1);
            s2 = fmaf(fmaxf(a2_[u][3], 0.f), h4[2][3], s2);
            s3 = fmaf(fmaxf(a3_[u][3], 0.f), h4[3][3], s3);
            float ts = (s0 + s1) + (s2 + s3);
            ts += __shfl_xor(ts, 16);
            ts += __shfl_xor(ts, 32);
            if (lg == 0 && p_[u] < NUM_P) {
                sq_s[p_[u]] = make_float2(ts, aq_[u][0]);   // q at C row 0
            }
        }
    }
    __syncthreads();

    // ---------------- phase 3: softmax + pooling (wave reductions) ----------------
    float sv[3], qv[3];
    #pragma unroll
    for (int i = 0; i < 3; ++i) {
        int p = t + i * 256;
        bool ok = p < NUM_P;
        float2 sq = ok ? sq_s[p] : make_float2(-1e30f, 0.f);
        sv[i] = sq.x;
        qv[i] = sq.y;
    }

    float m3 = fmaxf(fmaxf(sv[0], sv[1]), sv[2]);
    #pragma unroll
    for (int mm = 1; mm < 64; mm <<= 1) m3 = fmaxf(m3, __shfl_xor(m3, mm));
    if (lane == 0) wred[wave] = m3;
    __syncthreads();
    const float M = fmaxf(fmaxf(wred[0], wred[1]), fmaxf(wred[2], wred[3]));

    float S = 0.f, Q = 0.f;
    #pragma unroll
    for (int i = 0; i < 3; ++i) {
        float eo = __expf(sv[i] - M);
        S += eo;
        Q += eo * qv[i];
    }
    #pragma unroll
    for (int mm = 1; mm < 64; mm <<= 1) {
        S += __shfl_xor(S, mm);
        Q += __shfl_xor(Q, mm);
    }
    if (lane == 0) { wred[4 + wave] = S; wred[8 + wave] = Q; }
    __syncthreads();

    if (t == 0) {
        const float Ssum = wred[4] + wred[5] + wred[6] + wred[7];
        const float Qsum = wred[8] + wred[9] + wred[10] + wred[11];
        const float att_pool = Qsum / Ssum;
        const float x = bias[0] + s_yfirst + att_pool;
        out[b] = 1.f / (1.f + __expf(-x));
    }
}

extern "C" void kernel_launch(void* const* d_in, const int* in_sizes, int n_in,
                              void* d_out, int out_size, void* d_ws, size_t ws_size,
                              hipStream_t stream) {
    const int*   feat_index = (const int*)  d_in[0];
    const float* feat_value = (const float*)d_in[1];
    const float* fo_w       = (const float*)d_in[2];
    const float* emb_table  = (const float*)d_in[3];
    const float* att_W      = (const float*)d_in[4];
    const float* att_b      = (const float*)d_in[5];
    const float* att_h      = (const float*)d_in[6];
    const float* p_vec      = (const float*)d_in[7];
    const float* bias       = (const float*)d_in[8];
    float*       out        = (float*)d_out;

    const int B = in_sizes[0] / NUM_F;   // 2048

    afm_mfma3<<<B, 256, 0, stream>>>(feat_index, feat_value, fo_w, emb_table,
                                     att_W, att_b, att_h, p_vec, bias, out);
}

// Round 5
// 31.802 us; speedup vs baseline: 1.0940x; 1.0940x over previous
//
#include <hip/hip_runtime.h>
#include <hip/hip_fp16.h>

#define NUM_F  39
#define NUM_P  741      // 39*38/2
#define NT     48       // tiles, padded (47 real + 1 pad)
#define NPAD   768      // NT * 16
#define DIM    64
#define ESTRH  72       // padded fp16 row stride (halves); row stride = 144 B (16B-aligned)

typedef float    f32x4 __attribute__((ext_vector_type(4)));
typedef _Float16 f16x8 __attribute__((ext_vector_type(8)));

union H8 {
    f16x8    v;
    __half2  h2[4];
    _Float16 h[8];
};

__global__ __launch_bounds__(256, 4) void afm_mfma5(
    const int*   __restrict__ feat_index,   // [B, F]
    const float* __restrict__ feat_value,   // [B, F]
    const float* __restrict__ fo_w,         // [NUM_FEATS, 1]
    const float* __restrict__ emb_table,    // [NUM_FEATS, 64]
    const float* __restrict__ att_W,        // [64, 64] (d, a)
    const float* __restrict__ att_b,        // [64]
    const float* __restrict__ att_h,        // [64]
    const float* __restrict__ p_vec,        // [64]
    const float* __restrict__ bias,         // [1]
    float*       __restrict__ out)          // [B]
{
    const int b    = blockIdx.x;
    const int t    = threadIdx.x;
    const int wave = t >> 6;
    const int lane = t & 63;
    const int la   = lane & 15;   // pair-within-tile (B col / C col)
    const int lg   = lane >> 4;   // k-group / C row-group

    __shared__ __half         e_lds[NUM_F][ESTRH];  // scaled embeddings, fp16
    __shared__ __half         Wt[DIM][ESTRH];       // W^T fp16: Wt[a][d]
    __shared__ float2         sq_s[NPAD];           // {sig, q}
    __shared__ float          b_lds[DIM], h_lds[DIM], pv_lds[DIM];
    __shared__ unsigned int   pairOff[NPAD];        // r*144 | (c*144 << 16)
    __shared__ int            s_idx[NUM_F];
    __shared__ float          s_fv[NUM_F];
    __shared__ float          s_yfirst;
    __shared__ float          wred[12];             // wave partials: max, S, Q

    // ---------------- phase 0: staging ----------------
    int   my_idx = 0;
    float my_fv  = 0.f;
    if (t < NUM_F) {
        my_idx   = feat_index[b * NUM_F + t];
        my_fv    = feat_value[b * NUM_F + t];
        s_idx[t] = my_idx;
        s_fv[t]  = my_fv;
    }
    if (t < DIM) {
        b_lds[t]  = att_b[t];
        h_lds[t]  = att_h[t];
        pv_lds[t] = p_vec[t];
    }
    if (t < NUM_F) {   // triu(k=1) pair map, row-major; store packed LDS byte offsets
        int r = t, off = r * (2 * NUM_F - r - 1) / 2;
        const unsigned int rb = (unsigned int)(r * (ESTRH * 2));
        for (int c = r + 1; c < NUM_F; ++c) {
            pairOff[off] = rb | ((unsigned int)(c * (ESTRH * 2)) << 16);
            ++off;
        }
    }
    if (t < NPAD - NUM_P) pairOff[NUM_P + t] = 0;   // pad -> row 0 reads, stores guarded

    // W^T -> fp16 LDS
    for (int q = t; q < DIM * DIM; q += 256) {
        int d = q >> 6, a = q & 63;
        Wt[a][d] = (__half)(_Float16)att_W[q];
    }

    // y_first: wave 0 butterfly
    float yf = (t < NUM_F) ? fo_w[my_idx] * my_fv : 0.f;
    if (wave == 0) {
        #pragma unroll
        for (int m = 1; m < 64; m <<= 1) yf += __shfl_xor(yf, m);
        if (t == 0) s_yfirst = yf;
    }
    __syncthreads();

    // ---------------- phase 1: E staging (fp16) ----------------
    {
        const float4* emb4 = (const float4*)emb_table;
        for (int q = t; q < NUM_F * 8; q += 256) {
            int f = q >> 3, d8 = q & 7;
            float4 v0 = emb4[(size_t)s_idx[f] * 16 + d8 * 2];
            float4 v1 = emb4[(size_t)s_idx[f] * 16 + d8 * 2 + 1];
            float fv = s_fv[f];
            H8 hh;
            hh.h2[0] = __float22half2_rn(make_float2(v0.x * fv, v0.y * fv));
            hh.h2[1] = __float22half2_rn(make_float2(v0.z * fv, v0.w * fv));
            hh.h2[2] = __float22half2_rn(make_float2(v1.x * fv, v1.y * fv));
            hh.h2[3] = __float22half2_rn(make_float2(v1.z * fv, v1.w * fv));
            *(f16x8*)&e_lds[f][d8 * 8] = hh.v;
        }
    }
    __syncthreads();

    // ---------------- hoisted stationary fragments ----------------
    // A-frags = W^T tiles: lane holds row a = n*16+la, k(d) = kf*32 + lg*8 + j
    f16x8 WA[4][2];
    #pragma unroll
    for (int n = 0; n < 4; ++n)
        #pragma unroll
        for (int kf = 0; kf < 2; ++kf)
            WA[n][kf] = *(const f16x8*)&Wt[n * 16 + la][kf * 32 + lg * 8];

    // p_vec as row 0 of a 5th A-tile
    f16x8 PA[2];
    #pragma unroll
    for (int kf = 0; kf < 2; ++kf) {
        H8 P;
        #pragma unroll
        for (int j = 0; j < 8; ++j) {
            float x = (la == 0) ? pv_lds[kf * 32 + lg * 8 + j] : 0.f;
            P.h[j] = (_Float16)x;
        }
        PA[kf] = P.v;
    }

    // bias (accum C-init) and h, per lane's C rows: a = n*16 + lg*4 + i
    f32x4 b4[4], h4[4];
    #pragma unroll
    for (int n = 0; n < 4; ++n) {
        b4[n] = *(const f32x4*)&b_lds[n * 16 + lg * 4];
        h4[n] = *(const f32x4*)&h_lds[n * 16 + lg * 4];
    }
    const f32x4 z4 = {0.f, 0.f, 0.f, 0.f};

    const char* e_base = (const char*)&e_lds[0][0];
    const int   lgo    = lg * 16;   // byte offset of this lane's 16B k-chunk

    // ---------------- phase 2: pair-tile loop (16 pairs / tile / wave) ----------------
    #pragma unroll 1
    for (int it = 0; it < 12; ++it) {
        const int tile = wave + it * 4;        // < 48
        const int p    = (tile << 4) + la;
        const unsigned int rc = pairOff[p];
        const unsigned int ro = rc & 0xFFFFu;
        const unsigned int co = rc >> 16;

        // B-frags = inter: col = la (pair), k(d) = kf*32 + lg*8 + j
        H8 er0, er1, ec0, ec1, B0, B1;
        er0.v = *(const f16x8*)(e_base + ro + lgo);
        er1.v = *(const f16x8*)(e_base + ro + lgo + 64);
        ec0.v = *(const f16x8*)(e_base + co + lgo);
        ec1.v = *(const f16x8*)(e_base + co + lgo + 64);
        #pragma unroll
        for (int i = 0; i < 4; ++i) {
            B0.h2[i] = __hmul2(er0.h2[i], ec0.h2[i]);
            B1.h2[i] = __hmul2(er1.h2[i], ec1.h2[i]);
        }

        // Z^T tiles: D[a][pair]; bias enters as the first MFMA's C operand
        f32x4 a0 = __builtin_amdgcn_mfma_f32_16x16x32_f16(WA[0][0], B0.v, b4[0], 0, 0, 0);
        f32x4 a1 = __builtin_amdgcn_mfma_f32_16x16x32_f16(WA[1][0], B0.v, b4[1], 0, 0, 0);
        f32x4 a2 = __builtin_amdgcn_mfma_f32_16x16x32_f16(WA[2][0], B0.v, b4[2], 0, 0, 0);
        f32x4 a3 = __builtin_amdgcn_mfma_f32_16x16x32_f16(WA[3][0], B0.v, b4[3], 0, 0, 0);
        f32x4 aq = __builtin_amdgcn_mfma_f32_16x16x32_f16(PA[0],    B0.v, z4,    0, 0, 0);
        a0 = __builtin_amdgcn_mfma_f32_16x16x32_f16(WA[0][1], B1.v, a0, 0, 0, 0);
        a1 = __builtin_amdgcn_mfma_f32_16x16x32_f16(WA[1][1], B1.v, a1, 0, 0, 0);
        a2 = __builtin_amdgcn_mfma_f32_16x16x32_f16(WA[2][1], B1.v, a2, 0, 0, 0);
        a3 = __builtin_amdgcn_mfma_f32_16x16x32_f16(WA[3][1], B1.v, a3, 0, 0, 0);
        aq = __builtin_amdgcn_mfma_f32_16x16x32_f16(PA[1],    B1.v, aq, 0, 0, 0);

        // epilogue: sig[pair] = sum_a relu(Zt[a][pair]) * h[a]; 4-way partial tree
        float s0 = fmaxf(a0[0], 0.f) * h4[0][0];
        float s1 = fmaxf(a1[0], 0.f) * h4[1][0];
        float s2 = fmaxf(a2[0], 0.f) * h4[2][0];
        float s3 = fmaxf(a3[0], 0.f) * h4[3][0];
        s0 = fmaf(fmaxf(a0[1], 0.f), h4[0][1], s0);
        s1 = fmaf(fmaxf(a1[1], 0.f), h4[1][1], s1);
        s2 = fmaf(fmaxf(a2[1], 0.f), h4[2][1], s2);
        s3 = fmaf(fmaxf(a3[1], 0.f), h4[3][1], s3);
        s0 = fmaf(fmaxf(a0[2], 0.f), h4[0][2], s0);
        s1 = fmaf(fmaxf(a1[2], 0.f), h4[1][2], s1);
        s2 = fmaf(fmaxf(a2[2], 0.f), h4[2][2], s2);
        s3 = fmaf(fmaxf(a3[2], 0.f), h4[3][2], s3);
        s0 = fmaf(fmaxf(a0[3], 0.f), h4[0][3], s0);
        s1 = fmaf(fmaxf(a1[3], 0.f), h4[1][3], s1);
        s2 = fmaf(fmaxf(a2[3], 0.f), h4[2][3], s2);
        s3 = fmaf(fmaxf(a3[3], 0.f), h4[3][3], s3);
        float ts = (s0 + s1) + (s2 + s3);
        ts += __shfl_xor(ts, 16);
        ts += __shfl_xor(ts, 32);

        if (lg == 0 && p < NUM_P) {
            sq_s[p] = make_float2(ts, aq[0]);   // q at C row 0
        }
    }
    __syncthreads();

    // ---------------- phase 3: softmax + pooling (wave reductions) ----------------
    float sv[3], qv[3];
    #pragma unroll
    for (int i = 0; i < 3; ++i) {
        int p = t + i * 256;
        bool ok = p < NUM_P;
        float2 sq = ok ? sq_s[p] : make_float2(-1e30f, 0.f);
        sv[i] = sq.x;
        qv[i] = sq.y;
    }

    float m3 = fmaxf(fmaxf(sv[0], sv[1]), sv[2]);
    #pragma unroll
    for (int mm = 1; mm < 64; mm <<= 1) m3 = fmaxf(m3, __shfl_xor(m3, mm));
    if (lane == 0) wred[wave] = m3;
    __syncthreads();
    const float M = fmaxf(fmaxf(wred[0], wred[1]), fmaxf(wred[2], wred[3]));

    float S = 0.f, Q = 0.f;
    #pragma unroll
    for (int i = 0; i < 3; ++i) {
        float eo = __expf(sv[i] - M);
        S += eo;
        Q += eo * qv[i];
    }
    #pragma unroll
    for (int mm = 1; mm < 64; mm <<= 1) {
        S += __shfl_xor(S, mm);
        Q += __shfl_xor(Q, mm);
    }
    if (lane == 0) { wred[4 + wave] = S; wred[8 + wave] = Q; }
    __syncthreads();

    if (t == 0) {
        const float Ssum = wred[4] + wred[5] + wred[6] + wred[7];
        const float Qsum = wred[8] + wred[9] + wred[10] + wred[11];
        const float att_pool = Qsum / Ssum;
        const float x = bias[0] + s_yfirst + att_pool;
        out[b] = 1.f / (1.f + __expf(-x));
    }
}

extern "C" void kernel_launch(void* const* d_in, const int* in_sizes, int n_in,
                              void* d_out, int out_size, void* d_ws, size_t ws_size,
                              hipStream_t stream) {
    const int*   feat_index = (const int*)  d_in[0];
    const float* feat_value = (const float*)d_in[1];
    const float* fo_w       = (const float*)d_in[2];
    const float* emb_table  = (const float*)d_in[3];
    const float* att_W      = (const float*)d_in[4];
    const float* att_b      = (const float*)d_in[5];
    const float* att_h      = (const float*)d_in[6];
    const float* p_vec      = (const float*)d_in[7];
    const float* bias       = (const float*)d_in[8];
    float*       out        = (float*)d_out;

    const int B = in_sizes[0] / NUM_F;   // 2048

    afm_mfma5<<<B, 256, 0, stream>>>(feat_index, feat_value, fo_w, emb_table,
                                     att_W, att_b, att_h, p_vec, bias, out);
}